// Round 5
// baseline (278.064 us; speedup 1.0000x reference)
//
#include <hip/hip_runtime.h>
#include <hip/hip_bf16.h>

// SDPA with materialized attention output — fused, pipelined, packed-cvt version.
// B=16, LQ=LK=2048, D=64. d_out = out [B,LQ,D] f32 then attn [B,LQ,LK] f32.
namespace {
constexpr int kB = 16;
constexpr int kLQ = 2048;
constexpr int kLK = 2048;
constexpr int kD = 64;
constexpr int kQBlk = 16;              // q rows per workgroup
constexpr int kStride = 2056;          // LDS row stride in bf16 elems (2048 + 8 pad)
constexpr float kLog2e = 1.44269504088896340736f;
}

using short8 = __attribute__((ext_vector_type(8))) short;
using f32x4 = __attribute__((ext_vector_type(4))) float;

union S8U { short8 v; unsigned u[4]; unsigned long long q[2]; };

static __device__ __forceinline__ unsigned pk2(float lo, float hi) {
    // v_cvt_pk_bf16_f32 via the compiler path; bfloat162 isn't trivially
    // copyable so assemble the word from the two u16 members.
    __hip_bfloat162 h = __float22bfloat162_rn(float2{lo, hi});
    unsigned short a = __builtin_bit_cast(unsigned short, h.x);
    unsigned short b = __builtin_bit_cast(unsigned short, h.y);
    return (unsigned)a | ((unsigned)b << 16);
}
static __device__ __forceinline__ float bf2f(unsigned short s) {
    unsigned u = ((unsigned)s) << 16;
    return __builtin_bit_cast(float, u);
}
static __device__ __forceinline__ short8 cvt8(float4 a, float4 b) {
    S8U r;
    r.u[0] = pk2(a.x, a.y); r.u[1] = pk2(a.z, a.w);
    r.u[2] = pk2(b.x, b.y); r.u[3] = pk2(b.z, b.w);
    return r.v;
}

__global__ __launch_bounds__(512, 4) void sdpa_v5_kernel(
    const float* __restrict__ qg, const float* __restrict__ kg,
    const float* __restrict__ vg, const void* __restrict__ maskg,
    float* __restrict__ outg, float* __restrict__ attng)
{
    __shared__ unsigned short s_s[kQBlk][kStride];   // e = exp(S)*!mask (bf16, unnormalized)
    __shared__ float s_wsum[8][16];                  // per-wave partial row sums
    __shared__ float s_red[kQBlk][kD];               // PV k-split reduction scratch
    __shared__ int s_flag;

    const int tid = threadIdx.x;
    const int wave = tid >> 6;
    const int lane = tid & 63;
    const int r16 = lane & 15;
    const int g = lane >> 4;

    const int blk = blockIdx.x;
    const int b = blk >> 7;                  // / 128
    const int qrow0 = (blk & 127) * kQBlk;

    // ---- mask dtype detection: int32 0/1 words have bytes 1..3 == 0 ----
    if (tid < 64) {
        unsigned w = ((const unsigned*)maskg)[tid];
        unsigned long long bal = __ballot((w & 0xFFFFFF00u) != 0u);
        if (tid == 0) s_flag = (bal != 0ull) ? 1 : 0;
    }
    __syncthreads();
    const bool mask_byte = (s_flag != 0);
    const unsigned char* mask_u8 = (const unsigned char*)maskg;
    const int* mask_i32 = (const int*)maskg;

    // ---- Q fragment: q[qrow0+r16][8g+j] * (0.125*log2e) -> exp2 later is exact hw ----
    short8 q0, q1;
    {
        const float4* qp = (const float4*)(qg + ((size_t)b * kLQ + qrow0 + r16) * kD);
        const float s = 0.125f * kLog2e;
        float4 x0 = qp[2*g + 0], x1 = qp[2*g + 1];
        float4 x2 = qp[2*g + 8], x3 = qp[2*g + 9];
        x0 *= s; x1 *= s; x2 *= s; x3 *= s;
        q0 = cvt8(x0, x1);
        q1 = cvt8(x2, x3);
    }
    const size_t kbase = (size_t)b * kLK * kD;
    const size_t mrowL = ((size_t)b * kLQ + qrow0 + r16) * (size_t)kLK;  // mask row for this lane
    float wsum = 0.f;

    // ---- hoist mask words for all 8 tiles (byte path) ----
    unsigned hmA[8], hmB[8];
    if (mask_byte) {
#pragma unroll
        for (int i = 0; i < 8; ++i) {
            const int c0 = (wave + 8 * i) * 32;
            hmA[i] = *(const unsigned*)(mask_u8 + mrowL + c0 + 4*g);
            hmB[i] = *(const unsigned*)(mask_u8 + mrowL + c0 + 16 + 4*g);
        }
    }

    // ---- Phase 1: e = !mask * exp2(QK^T*log2e/8) -> LDS bf16, + per-row sums ----
    float4 cur[8], nxt[8];
    {
        const int col0 = wave * 32;
        const float4* kpA = (const float4*)(kg + kbase + (size_t)(col0 + r16) * kD);
        const float4* kpB = (const float4*)(kg + kbase + (size_t)(col0 + 16 + r16) * kD);
        cur[0] = kpA[2*g]; cur[1] = kpA[2*g+1]; cur[2] = kpA[2*g+8]; cur[3] = kpA[2*g+9];
        cur[4] = kpB[2*g]; cur[5] = kpB[2*g+1]; cur[6] = kpB[2*g+8]; cur[7] = kpB[2*g+9];
    }
#pragma unroll
    for (int i = 0; i < 8; ++i) {
        const int t = wave + 8 * i;
        const int col0 = t * 32;
        if (i < 7) {   // issue next tile's K loads before computing current
            const int nc0 = (t + 8) * 32;
            const float4* kpA = (const float4*)(kg + kbase + (size_t)(nc0 + r16) * kD);
            const float4* kpB = (const float4*)(kg + kbase + (size_t)(nc0 + 16 + r16) * kD);
            nxt[0] = kpA[2*g]; nxt[1] = kpA[2*g+1]; nxt[2] = kpA[2*g+8]; nxt[3] = kpA[2*g+9];
            nxt[4] = kpB[2*g]; nxt[5] = kpB[2*g+1]; nxt[6] = kpB[2*g+8]; nxt[7] = kpB[2*g+9];
        }
        const short8 kA0 = cvt8(cur[0], cur[1]);
        const short8 kA1 = cvt8(cur[2], cur[3]);
        const short8 kB0 = cvt8(cur[4], cur[5]);
        const short8 kB1 = cvt8(cur[6], cur[7]);
        f32x4 accA = {0.f, 0.f, 0.f, 0.f}, accB = {0.f, 0.f, 0.f, 0.f};
        // swapped operands: lane reg r holds S[q=r16][kcol = colbase + 4g + r]
        accA = __builtin_amdgcn_mfma_f32_16x16x32_bf16(kA0, q0, accA, 0, 0, 0);
        accA = __builtin_amdgcn_mfma_f32_16x16x32_bf16(kA1, q1, accA, 0, 0, 0);
        accB = __builtin_amdgcn_mfma_f32_16x16x32_bf16(kB0, q0, accB, 0, 0, 0);
        accB = __builtin_amdgcn_mfma_f32_16x16x32_bf16(kB1, q1, accB, 0, 0, 0);

        const int cA = col0 + 4*g;        // accA cols [cA, cA+4), row r16
        const int cB = col0 + 16 + 4*g;   // accB cols
        unsigned mwA, mwB;
        if (mask_byte) {
            mwA = hmA[i]; mwB = hmB[i];
        } else {
            const int4 a = *(const int4*)(mask_i32 + mrowL + cA);
            const int4 c = *(const int4*)(mask_i32 + mrowL + cB);
            mwA = (a.x ? 1u : 0u) | (a.y ? 0x100u : 0u) | (a.z ? 0x10000u : 0u) | (a.w ? 0x1000000u : 0u);
            mwB = (c.x ? 1u : 0u) | (c.y ? 0x100u : 0u) | (c.z ? 0x10000u : 0u) | (c.w ? 0x1000000u : 0u);
        }
        float eA[4], eB[4];
#pragma unroll
        for (int r = 0; r < 4; ++r) {
            eA[r] = ((mwA >> (8*r)) & 0xFFu) ? 0.f : __builtin_amdgcn_exp2f(accA[r]);
            eB[r] = ((mwB >> (8*r)) & 0xFFu) ? 0.f : __builtin_amdgcn_exp2f(accB[r]);
        }
        wsum += (eA[0] + eA[1]) + (eA[2] + eA[3]) + (eB[0] + eB[1]) + (eB[2] + eB[3]);
        S8U pA, pB;
        pA.u[0] = pk2(eA[0], eA[1]); pA.u[1] = pk2(eA[2], eA[3]);
        pB.u[0] = pk2(eB[0], eB[1]); pB.u[1] = pk2(eB[2], eB[3]);
        *(unsigned long long*)&s_s[r16][cA] = pA.q[0];
        *(unsigned long long*)&s_s[r16][cB] = pB.q[0];
#pragma unroll
        for (int j = 0; j < 8; ++j) cur[j] = nxt[j];   // static -> register rename
    }
    // row sum: combine the 4 lanes sharing r16 (xor 16, 32), stash per-wave
    wsum += __shfl_xor(wsum, 16, 64);
    wsum += __shfl_xor(wsum, 32, 64);
    if (g == 0) s_wsum[wave][r16] = wsum;
    __syncthreads();

    // ---- Phase 2a: attn = e * rinv -> global f32 (coalesced) ----
    {
        const int rr = tid >> 5;          // 0..15, 32 threads per row
        const int cc = tid & 31;
        float rsum = 0.f;
#pragma unroll
        for (int w = 0; w < 8; ++w) rsum += s_wsum[w][rr];
        const float rinv = __builtin_amdgcn_rcpf(rsum);
        float* arow = attng + ((size_t)b * kLQ + qrow0 + rr) * kLK;
#pragma unroll 4
        for (int i = 0; i < 16; ++i) {
            const int col = cc * 4 + i * 128;
            const unsigned long long sv = *(const unsigned long long*)&s_s[rr][col];
            float4 a;
            a.x = bf2f((unsigned short)(sv >>  0)) * rinv;
            a.y = bf2f((unsigned short)(sv >> 16)) * rinv;
            a.z = bf2f((unsigned short)(sv >> 32)) * rinv;
            a.w = bf2f((unsigned short)(sv >> 48)) * rinv;
            *(float4*)(arow + col) = a;
        }
    }

    // ---- Phase 2b: out = (e @ V) * rinv. wave (w&3) owns d-cols, (w>>2) k-half ----
    {
        const int d0 = (wave & 3) * 16;
        const int kh = wave >> 2;
        const float* vbase = vg + (size_t)b * kLK * kD + d0 + r16;
        float va[8], vb[8];
#pragma unroll
        for (int j = 0; j < 8; ++j) va[j] = vbase[(size_t)(kh*1024 + 8*g + j) * kD];
        f32x4 acc = {0.f, 0.f, 0.f, 0.f};
#pragma unroll
        for (int kt = 0; kt < 32; ++kt) {
            const int kk0 = (kh * 32 + kt) * 32 + 8 * g;
            float* cv = (kt & 1) ? vb : va;
            float* nv = (kt & 1) ? va : vb;
            if (kt < 31) {   // prefetch next 8 V values
#pragma unroll
                for (int j = 0; j < 8; ++j) nv[j] = vbase[(size_t)(kk0 + 32 + j) * kD];
            }
            const short8 af = *(const short8*)&s_s[r16][kk0];
            S8U bv;
            bv.u[0] = pk2(cv[0], cv[1]); bv.u[1] = pk2(cv[2], cv[3]);
            bv.u[2] = pk2(cv[4], cv[5]); bv.u[3] = pk2(cv[6], cv[7]);
            acc = __builtin_amdgcn_mfma_f32_16x16x32_bf16(af, bv.v, acc, 0, 0, 0);
        }
        if (kh == 1) {
#pragma unroll
            for (int r = 0; r < 4; ++r) s_red[4*g + r][d0 + r16] = acc[r];
        }
        __syncthreads();
        if (kh == 0) {
#pragma unroll
            for (int r = 0; r < 4; ++r) {
                const int m = 4*g + r;
                float rs = 0.f;
#pragma unroll
                for (int w = 0; w < 8; ++w) rs += s_wsum[w][m];
                outg[((size_t)b * kLQ + qrow0 + m) * kD + d0 + r16] =
                    (acc[r] + s_red[m][d0 + r16]) * __builtin_amdgcn_rcpf(rs);
            }
        }
    }
}

extern "C" void kernel_launch(void* const* d_in, const int* in_sizes, int n_in,
                              void* d_out, int out_size, void* d_ws, size_t ws_size,
                              hipStream_t stream) {
    (void)in_sizes; (void)n_in; (void)out_size; (void)d_ws; (void)ws_size;
    const float* q = (const float*)d_in[0];
    const float* k = (const float*)d_in[1];
    const float* v = (const float*)d_in[2];
    const void* mask = d_in[3];
    float* out = (float*)d_out;
    float* attn = out + (size_t)kB * kLQ * kD;
    const dim3 grid(kB * (kLQ / kQBlk));     // 2048 workgroups
    sdpa_v5_kernel<<<grid, 512, 0, stream>>>(q, k, v, mask, out, attn);
}